// Round 11
// baseline (6459.249 us; speedup 1.0000x reference)
//
#include <hip/hip_runtime.h>
#include <hip/hip_bf16.h>
#include <hip/hip_cooperative_groups.h>

namespace cg = cooperative_groups;

#define T_STEPS 512
// ws: Xf bf16 frag-major [0,32MiB) | tagged h ring 2 x 128KiB
#define RING_OFF 33554432u
#define WS_NEED  33816576u

typedef __attribute__((ext_vector_type(4))) float f32x4;
typedef __attribute__((ext_vector_type(8))) short short8;
typedef __attribute__((ext_vector_type(4))) unsigned int u32x4;

__device__ __forceinline__ short f2bf(float f) {
  __hip_bfloat16 h = __float2bfloat16(f);   // RNE
  return *reinterpret_cast<short*>(&h);
}
__device__ __forceinline__ unsigned bfbits(float f) {
  __hip_bfloat16 h = __float2bfloat16(f);
  return (unsigned)*reinterpret_cast<unsigned short*>(&h);
}
__device__ __forceinline__ short8 as_s8(u32x4 v) {
  union { u32x4 u; short8 s; } x; x.u = v; return x.s;
}

__global__ __launch_bounds__(512, 1) void lstm_kernel(
    const float* __restrict__ X, const float* __restrict__ W,
    const float* __restrict__ Bv, float* __restrict__ Out,
    char* __restrict__ ws)
{
  __shared__ char BxL[32768];       // x-half B-frags: [n 2][frag 16][lane 64]*16B

  const int tid  = threadIdx.x;
  const int wg   = blockIdx.x;      // 0..63 -> h cols [8wg, 8wg+8)
  const int lane = tid & 63;
  const int wv   = tid >> 6;        // 8 waves: m = wv>>1, n = wv&1
  const int m    = wv >> 1;
  const int n    = wv & 1;
  const int c16  = lane & 15;       // packed col = g*4 + q
  const int kgrp = lane >> 4;
  const int gg   = c16 >> 2;        // 0=f 1=i 2=g 3=o
  const int q    = c16 & 3;

  char* Xf   = ws;
  char* ring = ws + RING_OFF;

  // ---- zero both ring slots (replay-safe: stale tag 511 would alias at t=511) ----
  {
    const int id = wg * 512 + tid;
    if (id < 16384) {
      u32x4 z = {0u, 0u, 0u, 0u};
      char* p = ring + (size_t)id * 16;
      asm volatile("global_store_dwordx4 %0, %1, off sc0 sc1" :: "v"(p), "v"(z) : "memory");
    }
  }

  // ---- one-time: X (fp32) -> Xf (bf16, A-frag-major) [round-5 verified] ----
  for (int id = wg * 512 + tid; id < 512 * 64 * 64; id += 64 * 512) {
    const int c8  = id & 63;
    const int row = (id >> 6) & 63;
    const int t   = id >> 12;
    const float* xp = X + ((size_t)(t * 64 + row)) * 512 + c8 * 8;
    const float4 a = *(const float4*)xp;
    const float4 b = *(const float4*)(xp + 4);
    short8 v;
    v[0]=f2bf(a.x); v[1]=f2bf(a.y); v[2]=f2bf(a.z); v[3]=f2bf(a.w);
    v[4]=f2bf(b.x); v[5]=f2bf(b.y); v[6]=f2bf(b.z); v[7]=f2bf(b.w);
    *(short8*)(Xf + (size_t)t * 65536 + (row >> 4) * 16384 + (c8 >> 2) * 1024
               + ((((c8 & 3) << 4) | (row & 15))) * 16) = v;
  }
  __threadfence();                                   // write back dirty L2 (Xf)
  cg::this_grid().sync();
  __builtin_amdgcn_fence(__ATOMIC_ACQUIRE, "agent"); // one-time inv of stale clean lines

  // ---- W: h-half -> 16 register fragments; x-half -> LDS frags [verified] ----
  const int gcol = gg * 512 + wg * 8 + n * 4 + q;    // actual W column
  short8 Bh[16];
  #pragma unroll
  for (int kk = 0; kk < 16; ++kk) {
    short8 v;
    #pragma unroll
    for (int j = 0; j < 8; ++j)
      v[j] = f2bf(W[(size_t)(512 + kk * 32 + kgrp * 8 + j) * 2048 + gcol]);
    Bh[kk] = v;
  }
  if (wv < 2) {
    for (int f = 0; f < 16; ++f) {
      short8 v;
      #pragma unroll
      for (int j = 0; j < 8; ++j)
        v[j] = f2bf(W[(size_t)(f * 32 + kgrp * 8 + j) * 2048 + gcol]);
      *(short8*)(BxL + wv * 16384 + f * 1024 + lane * 16) = v;
    }
  }
  __syncthreads();
  const float bias = Bv[gcol];

  float cst[4] = {0.f, 0.f, 0.f, 0.f};
  const int prow = m * 16 + c16;    // consumer A row

  // ---- x-prefetch (round-8 verified: early-clobber asm) ----
  u32x4 x0,x1,x2,x3,x4,x5,x6,x7,x8,x9,x10,x11,x12,x13,x14,x15;
  #define PFX4(base, o0, o1, o2, o3) \
    asm volatile( \
      "global_load_dwordx4 %0, %4, off\n\t"             \
      "global_load_dwordx4 %1, %4, off offset:1024\n\t" \
      "global_load_dwordx4 %2, %4, off offset:2048\n\t" \
      "global_load_dwordx4 %3, %4, off offset:3072"     \
      : "=&v"(o0), "=&v"(o1), "=&v"(o2), "=&v"(o3) : "v"(base))
  #define PFX(tt) do { \
    const char* xb_ = Xf + (size_t)(tt) * 65536 + m * 16384 + lane * 16; \
    PFX4(xb_,          x0,  x1,  x2,  x3);  \
    PFX4(xb_ + 4096,   x4,  x5,  x6,  x7);  \
    PFX4(xb_ + 8192,   x8,  x9,  x10, x11); \
    PFX4(xb_ + 12288,  x12, x13, x14, x15); \
  } while (0)

  // ---- tagged h-load: 8 dwordx4 per quarter, single base, literal offsets ----
  u32x4 ga0,gb0,ga1,gb1,ga2,gb2,ga3,gb3;   // set A (quarters 0,2)
  u32x4 ga4,gb4,ga5,gb5,ga6,gb6,ga7,gb7;   // set B (quarters 1,3)
  #define LQ8(B_, O0,O1,O2,O3,O4,O5,O6,O7, v0,v1,v2,v3,v4,v5,v6,v7) \
    asm volatile( \
      "global_load_dwordx4 %0, %8, off offset:" #O0 " sc0 sc1\n\t" \
      "global_load_dwordx4 %1, %8, off offset:" #O1 " sc0 sc1\n\t" \
      "global_load_dwordx4 %2, %8, off offset:" #O2 " sc0 sc1\n\t" \
      "global_load_dwordx4 %3, %8, off offset:" #O3 " sc0 sc1\n\t" \
      "global_load_dwordx4 %4, %8, off offset:" #O4 " sc0 sc1\n\t" \
      "global_load_dwordx4 %5, %8, off offset:" #O5 " sc0 sc1\n\t" \
      "global_load_dwordx4 %6, %8, off offset:" #O6 " sc0 sc1\n\t" \
      "global_load_dwordx4 %7, %8, off offset:" #O7 " sc0 sc1"     \
      : "=&v"(v0),"=&v"(v1),"=&v"(v2),"=&v"(v3), \
        "=&v"(v4),"=&v"(v5),"=&v"(v6),"=&v"(v7) : "v"(B_))
  #define LQ_Q0(B_) LQ8(B_, 0,16,128,144,256,272,384,400,        ga0,gb0,ga1,gb1,ga2,gb2,ga3,gb3)
  #define LQ_Q1(B_) LQ8(B_, 512,528,640,656,768,784,896,912,     ga4,gb4,ga5,gb5,ga6,gb6,ga7,gb7)
  #define LQ_Q2(B_) LQ8(B_, 1024,1040,1152,1168,1280,1296,1408,1424, ga0,gb0,ga1,gb1,ga2,gb2,ga3,gb3)
  #define LQ_Q3(B_) LQ8(B_, 1536,1552,1664,1680,1792,1808,1920,1936, ga4,gb4,ga5,gb5,ga6,gb6,ga7,gb7)

  #define VQ4(p0,q0_,p1,q1_,p2,q2_,p3,q3_) \
    ((((p0.x^tg)|(p0.z^tg)|(q0_.x^tg)|(q0_.z^tg)) | \
      ((p1.x^tg)|(p1.z^tg)|(q1_.x^tg)|(q1_.z^tg)) | \
      ((p2.x^tg)|(p2.z^tg)|(q2_.x^tg)|(q2_.z^tg)) | \
      ((p3.x^tg)|(p3.z^tg)|(q3_.x^tg)|(q3_.z^tg))) & 0xffffu)

  #define HF(GA,GB,BI,ACC) { u32x4 dv; \
    dv.x = (GA.x >> 16) | (GA.y & 0xffff0000u); \
    dv.y = (GA.z >> 16) | (GA.w & 0xffff0000u); \
    dv.z = (GB.x >> 16) | (GB.y & 0xffff0000u); \
    dv.w = (GB.z >> 16) | (GB.w & 0xffff0000u); \
    ACC = __builtin_amdgcn_mfma_f32_16x16x32_bf16(as_s8(dv), Bh[BI], ACC, 0, 0, 0); }

  // counted wait; falls back to vmcnt(0) after any retry (stale-reg hazard guard)
  #define WAITC(N) do { \
    if (__builtin_expect(rty, 0)) asm volatile("s_waitcnt vmcnt(0)" ::: "memory"); \
    else asm volatile("s_waitcnt vmcnt(" #N ")" ::: "memory"); \
    __builtin_amdgcn_sched_barrier(0); } while (0)

  PFX(0);
  asm volatile("s_waitcnt vmcnt(0)" ::: "memory");
  __builtin_amdgcn_sched_barrier(0);

  for (int t = 0; t < T_STEPS; ++t) {
    // top wait: x(t) regs already drained in iter t-1; only ring/Out stores float
    asm volatile("s_waitcnt vmcnt(8)" ::: "memory");
    __builtin_amdgcn_sched_barrier(0);

    f32x4 ac0 = {0,0,0,0}, ac1 = {0,0,0,0}, ac2 = {0,0,0,0}, ac3 = {0,0,0,0};
    const char* bxp = BxL + n * 16384 + lane * 16;
    #define XM(i, ACC) ACC = __builtin_amdgcn_mfma_f32_16x16x32_bf16( \
        as_s8(x##i), *(const short8*)(bxp + i * 1024), ACC, 0, 0, 0)
    XM(0,ac0);  XM(1,ac1);  XM(2,ac2);  XM(3,ac3);
    XM(4,ac0);  XM(5,ac1);  XM(6,ac2);  XM(7,ac3);
    XM(8,ac0);  XM(9,ac1);  XM(10,ac2); XM(11,ac3);
    XM(12,ac0); XM(13,ac1); XM(14,ac2); XM(15,ac3);
    #undef XM

    if (t > 0) {
      const unsigned tg = (unsigned)t;
      // ---- detect: wave 0 polls each producer WG's LAST-issued granule TAG ----
      if (wv == 0) {
        const char* pp = ring + (size_t)((t - 1) & 1) * 131072 + 63 * 2048
                       + ((size_t)lane * 2 + 1) * 16;
        unsigned v;
        do {
          asm volatile("global_load_dword %0, %1, off sc0 sc1\n\ts_waitcnt vmcnt(0)"
                       : "=v"(v) : "v"(pp) : "memory");
        } while (!__all((int)((v & 0xffffu) == tg)));   // r11 fix: mask bf16 half
      }
      __builtin_amdgcn_s_barrier();
      __builtin_amdgcn_sched_barrier(0);

      const char* hb = ring + (size_t)((t - 1) & 1) * 131072
                     + (size_t)prow * 2048 + kgrp * 32;
      unsigned rty = 0;
      LQ_Q0(hb); LQ_Q1(hb);
      PFX(t == T_STEPS - 1 ? t : t + 1);
      // FIFO now: [stores<=8][Q0 8][Q1 8][PFX 16]

      WAITC(24);                                   // drains stores+Q0
      while (__any((int)VQ4(ga0,gb0,ga1,gb1,ga2,gb2,ga3,gb3))) {
        rty = 1; LQ_Q0(hb);
        asm volatile("s_waitcnt vmcnt(0)" ::: "memory");
        __builtin_amdgcn_sched_barrier(0);
      }
      HF(ga0,gb0,0,ac0) HF(ga1,gb1,1,ac1) HF(ga2,gb2,2,ac2) HF(ga3,gb3,3,ac3)
      LQ_Q2(hb);                                   // FIFO: [Q1][PFX][Q2]

      WAITC(24);                                   // drains Q1
      while (__any((int)VQ4(ga4,gb4,ga5,gb5,ga6,gb6,ga7,gb7))) {
        rty = 1; LQ_Q1(hb);
        asm volatile("s_waitcnt vmcnt(0)" ::: "memory");
        __builtin_amdgcn_sched_barrier(0);
      }
      HF(ga4,gb4,4,ac0) HF(ga5,gb5,5,ac1) HF(ga6,gb6,6,ac2) HF(ga7,gb7,7,ac3)
      LQ_Q3(hb);                                   // FIFO: [PFX][Q2][Q3]

      WAITC(8);                                    // r11 fix: drains PFX+Q2 (was 24)
      while (__any((int)VQ4(ga0,gb0,ga1,gb1,ga2,gb2,ga3,gb3))) {
        rty = 1; LQ_Q2(hb);
        asm volatile("s_waitcnt vmcnt(0)" ::: "memory");
        __builtin_amdgcn_sched_barrier(0);
      }
      HF(ga0,gb0,8,ac0) HF(ga1,gb1,9,ac1) HF(ga2,gb2,10,ac2) HF(ga3,gb3,11,ac3)

      WAITC(0);                                    // r11 fix: drains Q3 (was 16)
      while (__any((int)VQ4(ga4,gb4,ga5,gb5,ga6,gb6,ga7,gb7))) {
        rty = 1; LQ_Q3(hb);
        asm volatile("s_waitcnt vmcnt(0)" ::: "memory");
        __builtin_amdgcn_sched_barrier(0);
      }
      HF(ga4,gb4,12,ac0) HF(ga5,gb5,13,ac1) HF(ga6,gb6,14,ac2) HF(ga7,gb7,15,ac3)
    } else {
      PFX(1);
    }

    // -------- pointwise [verified layout, shfl 4/8/12] --------
    float hv[4], cnv[4];
    #pragma unroll
    for (int r = 0; r < 4; ++r) {
      const float pre = ac0[r] + ac1[r] + ac2[r] + ac3[r] + bias;
      const float e   = __expf((gg == 2) ? -2.f * pre : -pre);
      const float act = (gg == 2) ? (2.f / (1.f + e) - 1.f) : (1.f / (1.f + e));
      const float vi  = __shfl_xor(act, 4);     // f-lane <- i
      const float vg  = __shfl_xor(act, 8);     // f-lane <- g
      const float cn  = act * cst[r] + vi * vg; // valid on f-lanes
      if (gg == 0) cst[r] = cn;
      const float e2  = __expf(-2.f * cn);
      float tn = 2.f / (1.f + e2) - 1.f;
      tn = __shfl_xor(tn, 12);                  // o-lane <- tanh(c_new)
      hv[r]  = act * tn;                        // valid on o-lanes
      cnv[r] = cn;
    }

    // -------- publish h_t: tagged granules, fire-and-forget [round-6 verified] --------
    {
      const unsigned tgp = (unsigned)(t + 1);
      char* rp = ring + (size_t)(t & 1) * 131072
               + (size_t)(m * 16 + kgrp * 4) * 2048 + (wg * 2 + n) * 16;
      #pragma unroll
      for (int r = 0; r < 4; ++r) {
        const unsigned w = (bfbits(hv[r]) << 16) | tgp;
        const unsigned x = (unsigned)__shfl_xor((int)w, 1);
        const unsigned y = (unsigned)__shfl_xor((int)w, 2);
        const unsigned z = (unsigned)__shfl_xor((int)x, 2);
        if (c16 == 12) {
          u32x4 gr; gr.x = w; gr.y = x; gr.z = y; gr.w = z;
          asm volatile("global_store_dwordx4 %0, %1, off sc0 sc1"
                       :: "v"(rp + (size_t)r * 2048), "v"(gr) : "memory");
        }
      }
    }

    // -------- Out stores (plain cached; float off the chain) --------
    const int hc = wg * 8 + n * 4 + q;
    if (gg == 3) {
      float* op = Out + ((size_t)t * 64 + m * 16 + kgrp * 4) * 512 + hc;
      #pragma unroll
      for (int r = 0; r < 4; ++r) op[(size_t)r * 512] = hv[r];
      if (t == T_STEPS - 1) {
        #pragma unroll
        for (int r = 0; r < 4; ++r)
          Out[16777216u + (size_t)(m * 16 + kgrp * 4 + r) * 512 + hc] = hv[r];     // hx
      }
    }
    if (gg == 0 && t == T_STEPS - 1) {
      #pragma unroll
      for (int r = 0; r < 4; ++r)
        Out[16777216u + 32768u + (size_t)(m * 16 + kgrp * 4 + r) * 512 + hc] = cnv[r]; // cx
    }
  }
  #undef PFX
  #undef PFX4
}

extern "C" void kernel_launch(void* const* d_in, const int* in_sizes, int n_in,
                              void* d_out, int out_size, void* d_ws, size_t ws_size,
                              hipStream_t stream) {
  if (ws_size < (size_t)WS_NEED) return;

  const float* X  = (const float*)d_in[0];
  const float* W  = (const float*)d_in[1];
  const float* Bv = (const float*)d_in[2];
  float* Out = (float*)d_out;
  char*  ws  = (char*)d_ws;

  void* args[5];
  args[0] = (void*)&X;
  args[1] = (void*)&W;
  args[2] = (void*)&Bv;
  args[3] = (void*)&Out;
  args[4] = (void*)&ws;
  hipLaunchCooperativeKernel((const void*)lstm_kernel, dim3(64), dim3(512),
                             args, 0, stream);
}

// Round 12
// 2541.184 us; speedup vs baseline: 2.5418x; 2.5418x over previous
//
#include <hip/hip_runtime.h>
#include <hip/hip_bf16.h>
#include <hip/hip_cooperative_groups.h>

namespace cg = cooperative_groups;

#define T_STEPS 512
// ws: Xf bf16 frag-major [0,32MiB) | ring 2 slots x 2 copies x 64KiB | flags 64x128B
#define RING_OFF 33554432u
#define FLAG_OFF 33816576u
#define WS_NEED  33824768u

typedef __attribute__((ext_vector_type(4))) float f32x4;
typedef __attribute__((ext_vector_type(8))) short short8;
typedef __attribute__((ext_vector_type(4))) unsigned int u32x4;

__device__ __forceinline__ short f2bf(float f) {
  __hip_bfloat16 h = __float2bfloat16(f);   // RNE
  return *reinterpret_cast<short*>(&h);
}
__device__ __forceinline__ unsigned bfbits(float f) {
  __hip_bfloat16 h = __float2bfloat16(f);
  return (unsigned)*reinterpret_cast<unsigned short*>(&h);
}
__device__ __forceinline__ short8 as_s8(u32x4 v) {
  union { u32x4 u; short8 s; } x; x.u = v; return x.s;
}

__global__ __launch_bounds__(512, 1) void lstm_kernel(
    const float* __restrict__ X, const float* __restrict__ W,
    const float* __restrict__ Bv, float* __restrict__ Out,
    char* __restrict__ ws)
{
  __shared__ char BxL[32768];       // x-half B-frags: [n 2][frag 16][lane 64]*16B

  const int tid  = threadIdx.x;
  const int wg   = blockIdx.x;      // 0..63 -> h cols [8wg, 8wg+8)
  const int lane = tid & 63;
  const int wv   = tid >> 6;        // 8 waves: m = wv>>1, n = wv&1
  const int m    = wv >> 1;
  const int n    = wv & 1;
  const int c16  = lane & 15;       // packed col = g*4 + q
  const int kgrp = lane >> 4;
  const int gg   = c16 >> 2;        // 0=f 1=i 2=g 3=o
  const int q    = c16 & 3;

  char*     Xf    = ws;
  char*     ring  = ws + RING_OFF;
  unsigned* flags = (unsigned*)(ws + FLAG_OFF);

  // ---- zero my flag (before grid sync; robust across graph replays) ----
  if (tid == 0)
    __hip_atomic_store(&flags[wg * 32], 0u, __ATOMIC_RELAXED, __HIP_MEMORY_SCOPE_AGENT);

  // ---- one-time: X (fp32) -> Xf (bf16, A-frag-major) [round-5 verified] ----
  for (int id = wg * 512 + tid; id < 512 * 64 * 64; id += 64 * 512) {
    const int c8  = id & 63;
    const int row = (id >> 6) & 63;
    const int t   = id >> 12;
    const float* xp = X + ((size_t)(t * 64 + row)) * 512 + c8 * 8;
    const float4 a = *(const float4*)xp;
    const float4 b = *(const float4*)(xp + 4);
    short8 v;
    v[0]=f2bf(a.x); v[1]=f2bf(a.y); v[2]=f2bf(a.z); v[3]=f2bf(a.w);
    v[4]=f2bf(b.x); v[5]=f2bf(b.y); v[6]=f2bf(b.z); v[7]=f2bf(b.w);
    *(short8*)(Xf + (size_t)t * 65536 + (row >> 4) * 16384 + (c8 >> 2) * 1024
               + ((((c8 & 3) << 4) | (row & 15))) * 16) = v;
  }
  __threadfence();                                   // write back dirty L2 (Xf)
  cg::this_grid().sync();
  __builtin_amdgcn_fence(__ATOMIC_ACQUIRE, "agent"); // one-time inv of stale clean lines

  // ---- W: h-half -> 16 register fragments; x-half -> LDS frags [verified] ----
  const int gcol = gg * 512 + wg * 8 + n * 4 + q;    // actual W column
  short8 Bh[16];
  #pragma unroll
  for (int kk = 0; kk < 16; ++kk) {
    short8 v;
    #pragma unroll
    for (int j = 0; j < 8; ++j)
      v[j] = f2bf(W[(size_t)(512 + kk * 32 + kgrp * 8 + j) * 2048 + gcol]);
    Bh[kk] = v;
  }
  if (wv < 2) {
    for (int f = 0; f < 16; ++f) {
      short8 v;
      #pragma unroll
      for (int j = 0; j < 8; ++j)
        v[j] = f2bf(W[(size_t)(f * 32 + kgrp * 8 + j) * 2048 + gcol]);
      *(short8*)(BxL + wv * 16384 + f * 1024 + lane * 16) = v;
    }
  }
  __syncthreads();
  const float bias = Bv[gcol];

  float cst[4] = {0.f, 0.f, 0.f, 0.f};

  // ---- x-prefetch (round-8 verified: early-clobber asm) ----
  u32x4 x0,x1,x2,x3,x4,x5,x6,x7,x8,x9,x10,x11,x12,x13,x14,x15;
  #define PFX4(base, o0, o1, o2, o3) \
    asm volatile( \
      "global_load_dwordx4 %0, %4, off\n\t"             \
      "global_load_dwordx4 %1, %4, off offset:1024\n\t" \
      "global_load_dwordx4 %2, %4, off offset:2048\n\t" \
      "global_load_dwordx4 %3, %4, off offset:3072"     \
      : "=&v"(o0), "=&v"(o1), "=&v"(o2), "=&v"(o3) : "v"(base))
  #define PFX(tt) do { \
    const char* xb_ = Xf + (size_t)(tt) * 65536 + m * 16384 + lane * 16; \
    PFX4(xb_,          x0,  x1,  x2,  x3);  \
    PFX4(xb_ + 4096,   x4,  x5,  x6,  x7);  \
    PFX4(xb_ + 8192,   x8,  x9,  x10, x11); \
    PFX4(xb_ + 12288,  x12, x13, x14, x15); \
  } while (0)

  PFX(0);   // prologue

  for (int t = 0; t < T_STEPS; ++t) {
    // -------- consume prefetched x(t) (drained; stores may float, <=8) --------
    asm volatile("s_waitcnt vmcnt(8)" ::: "memory");
    __builtin_amdgcn_sched_barrier(0);

    f32x4 ac0 = {0,0,0,0}, ac1 = {0,0,0,0}, ac2 = {0,0,0,0}, ac3 = {0,0,0,0};
    const char* bxp = BxL + n * 16384 + lane * 16;
    #define XM(i, ACC) ACC = __builtin_amdgcn_mfma_f32_16x16x32_bf16( \
        as_s8(x##i), *(const short8*)(bxp + i * 1024), ACC, 0, 0, 0)
    XM(0,ac0);  XM(1,ac1);  XM(2,ac2);  XM(3,ac3);
    XM(4,ac0);  XM(5,ac1);  XM(6,ac2);  XM(7,ac3);
    XM(8,ac0);  XM(9,ac1);  XM(10,ac2); XM(11,ac3);
    XM(12,ac0); XM(13,ac1); XM(14,ac2); XM(15,ac3);
    #undef XM

    if (t > 0) {
      const unsigned tg = (unsigned)t;
      // ---- T1: pipelined 2-deep poll (wave 0; flags now 128B apart, T3) ----
      if (wv == 0) {
        const unsigned* fp = &flags[lane * 32];
        unsigned va, vb;
        asm volatile("global_load_dword %0, %1, off sc0 sc1"
                     : "=&v"(va) : "v"(fp) : "memory");
        for (;;) {
          asm volatile("global_load_dword %0, %1, off sc0 sc1"
                       : "=&v"(vb) : "v"(fp) : "memory");
          asm volatile("s_waitcnt vmcnt(1)" ::: "memory");
          __builtin_amdgcn_sched_barrier(0);
          if (__all((int)(va >= tg))) break;
          asm volatile("global_load_dword %0, %1, off sc0 sc1"
                       : "=&v"(va) : "v"(fp) : "memory");
          asm volatile("s_waitcnt vmcnt(1)" ::: "memory");
          __builtin_amdgcn_sched_barrier(0);
          if (__all((int)(vb >= tg))) break;
        }
        asm volatile("s_waitcnt vmcnt(0)" ::: "memory");   // drain trailing poll load
        __builtin_amdgcn_sched_barrier(0);
      }
      __builtin_amdgcn_s_barrier();      // raw: ordering via LLC-bypass loads below
      __builtin_amdgcn_sched_barrier(0); // pin h-loads after the barrier

      // ---- h-loads from MY copy (T2: copy per consumer n), then PFX(t+1) ----
      const char* hp0 = ring + (size_t)((t - 1) & 1) * 131072 + (size_t)n * 65536
                      + m * 16384 + lane * 16;
      const char* hp1 = hp0 + 4096;
      const char* hp2 = hp0 + 8192;
      const char* hp3 = hp0 + 12288;
      u32x4 h0,h1,h2,h3,h4,h5,h6,h7,h8,h9,h10,h11,h12,h13,h14,h15;
      #define LDR(base, off, vv) \
        asm volatile("global_load_dwordx4 %0, %1, off offset:" off " sc0 sc1" \
                     : "=&v"(vv) : "v"(base))
      LDR(hp0, "0", h0);  LDR(hp0, "1024", h1);  LDR(hp0, "2048", h2);  LDR(hp0, "3072", h3);
      LDR(hp1, "0", h4);  LDR(hp1, "1024", h5);  LDR(hp1, "2048", h6);  LDR(hp1, "3072", h7);
      LDR(hp2, "0", h8);  LDR(hp2, "1024", h9);  LDR(hp2, "2048", h10); LDR(hp2, "3072", h11);
      LDR(hp3, "0", h12); LDR(hp3, "1024", h13); LDR(hp3, "2048", h14); LDR(hp3, "3072", h15);
      #undef LDR
      PFX(t == T_STEPS - 1 ? t : t + 1);

      asm volatile("s_waitcnt vmcnt(16)" ::: "memory");   // oldest 16 = the h-loads
      __builtin_amdgcn_sched_barrier(0);                  // rule #18
      #define HM(i, ACC) ACC = __builtin_amdgcn_mfma_f32_16x16x32_bf16( \
          as_s8(h##i), Bh[i], ACC, 0, 0, 0)
      HM(0,ac0);  HM(1,ac1);  HM(2,ac2);  HM(3,ac3);
      HM(4,ac0);  HM(5,ac1);  HM(6,ac2);  HM(7,ac3);
      HM(8,ac0);  HM(9,ac1);  HM(10,ac2); HM(11,ac3);
      HM(12,ac0); HM(13,ac1); HM(14,ac2); HM(15,ac3);
      #undef HM
    } else {
      PFX(1);
    }

    // -------- pointwise [verified layout, shfl 4/8/12] --------
    float hv[4], cnv[4];
    #pragma unroll
    for (int r = 0; r < 4; ++r) {
      const float pre = ac0[r] + ac1[r] + ac2[r] + ac3[r] + bias;
      const float e   = __expf((gg == 2) ? -2.f * pre : -pre);
      const float act = (gg == 2) ? (2.f / (1.f + e) - 1.f) : (1.f / (1.f + e));
      const float vi  = __shfl_xor(act, 4);     // f-lane <- i
      const float vg  = __shfl_xor(act, 8);     // f-lane <- g
      const float cn  = act * cst[r] + vi * vg; // valid on f-lanes
      if (gg == 0) cst[r] = cn;
      const float e2  = __expf(-2.f * cn);
      float tn = 2.f / (1.f + e2) - 1.f;
      tn = __shfl_xor(tn, 12);                  // o-lane <- tanh(c_new)
      hv[r]  = act * tn;                        // valid on o-lanes
      cnv[r] = cn;
    }

    // -------- ring publish to BOTH copies [T2; verified packing] --------
    {
      char* rp = ring + (size_t)(t & 1) * 131072 + m * 16384 + (wg >> 2) * 1024
               + (((wg & 3) << 4) + kgrp * 4) * 16 + (n * 4 + q) * 2;
      #pragma unroll
      for (int r = 0; r < 4; ++r) {
        const unsigned hb = bfbits(hv[r]);
        const unsigned pb = (unsigned)__shfl_xor((int)hb, 1);  // partner col
        if (gg == 3 && !(q & 1)) {
          const unsigned pk = (hb & 0xffffu) | (pb << 16);
          unsigned* p0 = (unsigned*)(rp + (size_t)r * 16);
          asm volatile("global_store_dword %0, %2, off sc0 sc1\n\t"
                       "global_store_dword %1, %2, off sc0 sc1"
                       :: "v"(p0), "v"((char*)p0 + 65536), "v"(pk) : "memory");
        }
      }
    }

    // -------- drain ring stores, barrier, relaxed flag publish (r9-verified) --------
    asm volatile("s_waitcnt vmcnt(0)" ::: "memory");
    __builtin_amdgcn_sched_barrier(0);
    __builtin_amdgcn_s_barrier();
    if (tid == 0) {
      unsigned tv = (unsigned)(t + 1);
      unsigned* fp = &flags[wg * 32];
      asm volatile("global_store_dword %0, %1, off sc0 sc1"
                   :: "v"(fp), "v"(tv) : "memory");
    }

    const int hc = wg * 8 + n * 4 + q;
    if (gg == 3) {
      float* op = Out + ((size_t)t * 64 + m * 16 + kgrp * 4) * 512 + hc;
      #pragma unroll
      for (int r = 0; r < 4; ++r) op[(size_t)r * 512] = hv[r];
      if (t == T_STEPS - 1) {
        #pragma unroll
        for (int r = 0; r < 4; ++r)
          Out[16777216u + (size_t)(m * 16 + kgrp * 4 + r) * 512 + hc] = hv[r];     // hx
      }
    }
    if (gg == 0 && t == T_STEPS - 1) {
      #pragma unroll
      for (int r = 0; r < 4; ++r)
        Out[16777216u + 32768u + (size_t)(m * 16 + kgrp * 4 + r) * 512 + hc] = cnv[r]; // cx
    }
  }
  #undef PFX
  #undef PFX4
}

extern "C" void kernel_launch(void* const* d_in, const int* in_sizes, int n_in,
                              void* d_out, int out_size, void* d_ws, size_t ws_size,
                              hipStream_t stream) {
  if (ws_size < (size_t)WS_NEED) return;

  const float* X  = (const float*)d_in[0];
  const float* W  = (const float*)d_in[1];
  const float* Bv = (const float*)d_in[2];
  float* Out = (float*)d_out;
  char*  ws  = (char*)d_ws;

  void* args[5];
  args[0] = (void*)&X;
  args[1] = (void*)&W;
  args[2] = (void*)&Bv;
  args[3] = (void*)&Out;
  args[4] = (void*)&ws;
  hipLaunchCooperativeKernel((const void*)lstm_kernel, dim3(64), dim3(512),
                             args, 0, stream);
}